// Round 2
// baseline (2275.962 us; speedup 1.0000x reference)
//
#include <hip/hip_runtime.h>

#define S_SP   13824        // 24*24*24 spatial
#define CHAN   256
#define NQ     27648        // 2 * 13824
#define KCODES 2048
#define CS     3538944      // CHAN * S_SP
#define OFF_Q   1
#define OFF_PPL 7077889
#define OFF_ENC 7077890LL
#define OFF_IDX 63700994LL

typedef __bf16 bf16x8 __attribute__((ext_vector_type(8)));
typedef float  f32x4  __attribute__((ext_vector_type(4)));

__device__ __forceinline__ unsigned int f2bf(float f) {
  unsigned int u = __float_as_uint(f);
  unsigned int r = u + 0x7FFFu + ((u >> 16) & 1u);   // RNE
  return r >> 16;
}

// ---------------- prep_w: fp32 W -> bf16 Wb, plus wn = ||w||^2 ----------------
__global__ __launch_bounds__(256) void prep_w(const float* __restrict__ W,
                                              unsigned short* __restrict__ Wb,
                                              float* __restrict__ wn) {
  int g = blockIdx.x * 256 + threadIdx.x;
  int row = g >> 5;
  int d0 = (g & 31) * 8;
  const float* Wp = W + (size_t)row * CHAN + d0;
  float4 v0 = *(const float4*)Wp;
  float4 v1 = *(const float4*)(Wp + 4);
  float s = v0.x*v0.x + v0.y*v0.y + v0.z*v0.z + v0.w*v0.w
          + v1.x*v1.x + v1.y*v1.y + v1.z*v1.z + v1.w*v1.w;
  int4 p;
  p.x = (int)(f2bf(v0.x) | (f2bf(v0.y) << 16));
  p.y = (int)(f2bf(v0.z) | (f2bf(v0.w) << 16));
  p.z = (int)(f2bf(v1.x) | (f2bf(v1.y) << 16));
  p.w = (int)(f2bf(v1.z) | (f2bf(v1.w) << 16));
  *(int4*)(Wb + (size_t)row * CHAN + d0) = p;
  for (int off = 16; off; off >>= 1) s += __shfl_down(s, off);
  if ((threadIdx.x & 31) == 0) wn[row] = s;
}

// ---------------- prep_x: transpose [C][S] -> [n][d] and convert to bf16 ----------------
__global__ __launch_bounds__(256) void prep_x(const float* __restrict__ X,
                                              unsigned short* __restrict__ Xb) {
  __shared__ float xs[32 * 257];
  int t = threadIdx.x;
  int qb = blockIdx.x * 32;
  int b = qb / S_SP, s0 = qb % S_SP;
  const float* xp = X + (size_t)b * CS + s0;
  int q = t & 31;
  int db = t >> 5;                 // 0..7
  for (int r = 0; r < 32; ++r) {
    int d = db + (r << 3);
    xs[q * 257 + d] = xp[(size_t)d * S_SP + q];
  }
  __syncthreads();
  int row = t >> 3, c8 = t & 7;
  unsigned short* op = Xb + (size_t)(qb + row) * CHAN;
  const float* rp0 = xs + row * 257;
#pragma unroll
  for (int j = 0; j < 4; ++j) {
    int d = j * 64 + c8 * 8;
    const float* rp = rp0 + d;
    int4 p;
    p.x = (int)(f2bf(rp[0]) | (f2bf(rp[1]) << 16));
    p.y = (int)(f2bf(rp[2]) | (f2bf(rp[3]) << 16));
    p.z = (int)(f2bf(rp[4]) | (f2bf(rp[5]) << 16));
    p.w = (int)(f2bf(rp[6]) | (f2bf(rp[7]) << 16));
    *(int4*)(op + d) = p;
  }
}

// ---------------- dist_mfma: bf16 MFMA distances + argmin ----------------
// 64 q/block, 8 waves: qgroup=w&3 (16 q), kgroup=w>>2 (1024 codes).
// Per 16-code tile: 8x mfma_f32_16x16x32_bf16 over D=256.
// C layout: col=lane&15 (code), row=(lane>>4)*4+reg (query).
__global__ __launch_bounds__(512) void dist_mfma(const unsigned short* __restrict__ Xb,
                                                 const unsigned short* __restrict__ Wb,
                                                 const float* __restrict__ wn,
                                                 float* __restrict__ idx_out) {
  __shared__ float rB1[2][64], rB2[2][64];
  __shared__ int   rI1[2][64];
  int t = threadIdx.x;
  int w = t >> 6, l = t & 63;
  int qg = w & 3, kg = w >> 2;
  int qb = blockIdx.x * 64;
  int lr = l & 15, lc = l >> 4;

  bf16x8 a[8];
  const unsigned short* ap = Xb + (size_t)(qb + qg * 16 + lr) * CHAN + lc * 8;
#pragma unroll
  for (int c = 0; c < 8; ++c)
    a[c] = *(const bf16x8*)(ap + c * 32);

  float b1[4] = {3.4e38f, 3.4e38f, 3.4e38f, 3.4e38f};
  float b2[4] = {3.4e38f, 3.4e38f, 3.4e38f, 3.4e38f};
  int   i1[4] = {0, 0, 0, 0};

  const unsigned short* wp0 = Wb + (size_t)(kg * 1024 + lr) * CHAN + lc * 8;

  for (int it = 0; it < 64; ++it) {
    const unsigned short* wp = wp0 + (size_t)it * 16 * CHAN;
    f32x4 acc = {0.f, 0.f, 0.f, 0.f};
#pragma unroll
    for (int c = 0; c < 8; ++c) {
      bf16x8 bf = *(const bf16x8*)(wp + c * 32);
      acc = __builtin_amdgcn_mfma_f32_16x16x32_bf16(a[c], bf, acc, 0, 0, 0);
    }
    int k = kg * 1024 + it * 16 + lr;
    float wnk = wn[k];
#pragma unroll
    for (int r = 0; r < 4; ++r) {
      float sc = fmaf(-2.0f, acc[r], wnk);
      bool lt = sc < b1[r];
      b2[r] = fminf(b2[r], fmaxf(sc, b1[r]));
      b1[r] = lt ? sc : b1[r];
      i1[r] = lt ? k : i1[r];
    }
  }

  // reduce across the 16 code-lanes (xor over bits 0..3)
#pragma unroll
  for (int m = 1; m < 16; m <<= 1) {
#pragma unroll
    for (int r = 0; r < 4; ++r) {
      float ob1 = __shfl_xor(b1[r], m);
      int   oi1 = __shfl_xor(i1[r], m);
      float ob2 = __shfl_xor(b2[r], m);
      bool sw = (ob1 < b1[r]) || (ob1 == b1[r] && oi1 < i1[r]);
      b2[r] = fminf(fmaxf(b1[r], ob1), fminf(b2[r], ob2));
      b1[r] = sw ? ob1 : b1[r];
      i1[r] = sw ? oi1 : i1[r];
    }
  }
  if (lr == 0) {
#pragma unroll
    for (int r = 0; r < 4; ++r) {
      int ql = qg * 16 + lc * 4 + r;
      rB1[kg][ql] = b1[r]; rI1[kg][ql] = i1[r]; rB2[kg][ql] = b2[r];
    }
  }
  __syncthreads();
  if (t < 64) {
    float B1 = rB1[0][t]; int I1 = rI1[0][t]; float B2 = rB2[0][t];
    float c1 = rB1[1][t]; int ci = rI1[1][t]; float c2 = rB2[1][t];
    bool sw = (c1 < B1) || (c1 == B1 && ci < I1);
    float nb2 = fminf(fmaxf(B1, c1), fminf(B2, c2));
    float nb1 = sw ? c1 : B1;
    int   ni  = sw ? ci : I1;
    bool flag = (nb2 - nb1) < 3.0f;
    idx_out[qb + t] = flag ? -(float)(ni + 1) : (float)ni;
  }
}

// ---------------- refine: fp64 exact re-scan of flagged queries ----------------
__global__ __launch_bounds__(256) void refine(const float* __restrict__ X,
                                              const float* __restrict__ W,
                                              float* __restrict__ idx_out) {
  int n = blockIdx.x;
  if (idx_out[n] >= 0.f) return;
  int t = threadIdx.x;
  int b = n / S_SP, s = n % S_SP;

  __shared__ double xd[CHAN];
  xd[t] = (double)X[(size_t)b * CS + (size_t)t * S_SP + s];
  __syncthreads();

  double best = 1e300;
  int bi = 1 << 30;
  for (int j = 0; j < 8; ++j) {
    int k = t * 8 + j;
    const float* Wp = W + (size_t)k * CHAN;
    double dsum = 0.0;
    for (int d = 0; d < CHAN; ++d) {
      double df = xd[d] - (double)Wp[d];
      dsum = fma(df, df, dsum);
    }
    if (dsum < best) { best = dsum; bi = k; }
  }

  __shared__ double rv[256];
  __shared__ int    ri[256];
  rv[t] = best; ri[t] = bi;
  __syncthreads();
  for (int off = 128; off > 0; off >>= 1) {
    if (t < off) {
      if (rv[t + off] < rv[t] || (rv[t + off] == rv[t] && ri[t + off] < ri[t])) {
        rv[t] = rv[t + off]; ri[t] = ri[t + off];
      }
    }
    __syncthreads();
  }
  if (t == 0) idx_out[n] = (float)ri[0];
}

// ---------------- scatter_stats: gather quantized, one-hot, histogram, loss ----------------
__global__ __launch_bounds__(256) void scatter_stats(const float* __restrict__ X,
                                                     const float* __restrict__ W,
                                                     float* __restrict__ outF,
                                                     int* __restrict__ counts,
                                                     float* __restrict__ loss_acc) {
  __shared__ int h[KCODES];
  __shared__ float wred[4];
  int t = threadIdx.x;
  for (int j = t; j < KCODES; j += 256) h[j] = 0;
  __syncthreads();

  int n = blockIdx.x * 256 + t;
  int idx = (int)outF[OFF_IDX + n];
  atomicAdd(&h[idx], 1);
  outF[OFF_ENC + (size_t)n * KCODES + idx] = 1.0f;

  int b = n / S_SP, s = n % S_SP;
  const float* Wp = W + (size_t)idx * CHAN;
  const float* xp = X + (size_t)b * CS + s;
  float* qp = outF + OFF_Q + (size_t)b * CS + s;

  float lsum = 0.f;
#pragma unroll 4
  for (int c = 0; c < CHAN; ++c) {
    float wv = Wp[c];
    float xv = xp[(size_t)c * S_SP];
    qp[(size_t)c * S_SP] = wv;
    float df = wv - xv;
    lsum = fmaf(df, df, lsum);
  }

  for (int off = 32; off; off >>= 1) lsum += __shfl_down(lsum, off);
  if ((t & 63) == 0) wred[t >> 6] = lsum;
  __syncthreads();
  if (t == 0) atomicAdd(loss_acc, wred[0] + wred[1] + wred[2] + wred[3]);

  for (int j = t; j < KCODES; j += 256) {
    int v = h[j];
    if (v) atomicAdd(&counts[j], v);
  }
}

// ---------------- finalize ----------------
__global__ __launch_bounds__(256) void finalize(const int* __restrict__ counts,
                                                const float* __restrict__ loss_acc,
                                                float* __restrict__ outF) {
  __shared__ double red[256];
  int t = threadIdx.x;
  double H = 0.0;
  for (int k = t; k < KCODES; k += 256) {
    double p = (double)counts[k] / (double)NQ;
    H += p * log(p + 1e-10);
  }
  red[t] = H;
  __syncthreads();
  for (int off = 128; off > 0; off >>= 1) {
    if (t < off) red[t] += red[t + off];
    __syncthreads();
  }
  if (t == 0) {
    outF[0] = 0.25f * (loss_acc[0] / 7077888.0f);
    outF[OFF_PPL] = (float)exp(-red[0]);
  }
}

extern "C" void kernel_launch(void* const* d_in, const int* in_sizes, int n_in,
                              void* d_out, int out_size, void* d_ws, size_t ws_size,
                              hipStream_t stream) {
  const float* X = (const float*)d_in[0];
  const float* W = (const float*)d_in[1];
  float* outF = (float*)d_out;
  char* ws = (char*)d_ws;
  float* wn       = (float*)ws;                       // 8 KB
  int*   counts   = (int*)(ws + 8192);                // 8 KB
  float* loss_acc = (float*)(ws + 16384);             // 16 B
  unsigned short* Wb = (unsigned short*)(ws + 32768);          // 1 MB
  unsigned short* Xb = (unsigned short*)(ws + 32768 + 1048576); // ~14.2 MB

  hipMemsetAsync(ws + 8192, 0, 8192 + 16, stream);
  hipMemsetAsync((char*)d_out + OFF_ENC * 4, 0, (size_t)NQ * KCODES * 4, stream);

  prep_w<<<256, 256, 0, stream>>>(W, Wb, wn);
  prep_x<<<NQ / 32, 256, 0, stream>>>(X, Xb);
  dist_mfma<<<NQ / 64, 512, 0, stream>>>(Xb, Wb, wn, outF + OFF_IDX);
  refine<<<NQ, 256, 0, stream>>>(X, W, outF + OFF_IDX);
  scatter_stats<<<NQ / 256, 256, 0, stream>>>(X, W, outF, counts, loss_acc);
  finalize<<<1, 256, 0, stream>>>(counts, loss_acc, outF);
}

// Round 3
// 756.411 us; speedup vs baseline: 3.0089x; 3.0089x over previous
//
#include <hip/hip_runtime.h>

#define S_SP   13824        // 24*24*24 spatial
#define CHAN   256
#define NQ     27648        // 2 * 13824
#define KCODES 2048
#define CS     3538944      // CHAN * S_SP
#define OFF_Q   1
#define OFF_PPL 7077889
#define OFF_ENC 7077890LL
#define OFF_IDX 63700994LL

typedef __bf16 bf16x8 __attribute__((ext_vector_type(8)));
typedef float  f32x4  __attribute__((ext_vector_type(4)));

__device__ __forceinline__ unsigned int f2bf(float f) {
  unsigned int u = __float_as_uint(f);
  unsigned int r = u + 0x7FFFu + ((u >> 16) & 1u);   // RNE
  return r >> 16;
}
__device__ __forceinline__ float bf2f(unsigned int h) {
  return __uint_as_float(h << 16);
}
// split f into bf16 hi + bf16 lo
__device__ __forceinline__ void fsplit(float f, unsigned int& hi, unsigned int& lo) {
  hi = f2bf(f);
  float r = f - bf2f(hi);
  lo = f2bf(r);
}

// ---------------- prep_w: fp32 W -> bf16 Wh/Wl, plus wn = ||w||^2 ----------------
__global__ __launch_bounds__(256) void prep_w(const float* __restrict__ W,
                                              unsigned short* __restrict__ Wh,
                                              unsigned short* __restrict__ Wl,
                                              float* __restrict__ wn) {
  int g = blockIdx.x * 256 + threadIdx.x;
  int row = g >> 5;
  int d0 = (g & 31) * 8;
  const float* Wp = W + (size_t)row * CHAN + d0;
  float v[8];
  *(float4*)(v) = *(const float4*)Wp;
  *(float4*)(v + 4) = *(const float4*)(Wp + 4);
  float s = 0.f;
  unsigned int h[8], l[8];
#pragma unroll
  for (int j = 0; j < 8; ++j) {
    s = fmaf(v[j], v[j], s);
    fsplit(v[j], h[j], l[j]);
  }
  int4 ph, pl;
  ph.x = (int)(h[0] | (h[1] << 16)); ph.y = (int)(h[2] | (h[3] << 16));
  ph.z = (int)(h[4] | (h[5] << 16)); ph.w = (int)(h[6] | (h[7] << 16));
  pl.x = (int)(l[0] | (l[1] << 16)); pl.y = (int)(l[2] | (l[3] << 16));
  pl.z = (int)(l[4] | (l[5] << 16)); pl.w = (int)(l[6] | (l[7] << 16));
  *(int4*)(Wh + (size_t)row * CHAN + d0) = ph;
  *(int4*)(Wl + (size_t)row * CHAN + d0) = pl;
  for (int off = 16; off; off >>= 1) s += __shfl_down(s, off);
  if ((threadIdx.x & 31) == 0) wn[row] = s;
}

// ---------------- prep_x: transpose [C][S] -> [n][d], split to bf16 hi/lo ----------------
__global__ __launch_bounds__(256) void prep_x(const float* __restrict__ X,
                                              unsigned short* __restrict__ Xh,
                                              unsigned short* __restrict__ Xl) {
  __shared__ float xs[32 * 257];
  int t = threadIdx.x;
  int qb = blockIdx.x * 32;
  int b = qb / S_SP, s0 = qb % S_SP;
  const float* xp = X + (size_t)b * CS + s0;
  int q = t & 31;
  int db = t >> 5;                 // 0..7
  for (int r = 0; r < 32; ++r) {
    int d = db + (r << 3);
    xs[q * 257 + d] = xp[(size_t)d * S_SP + q];
  }
  __syncthreads();
  int row = t >> 3, c8 = t & 7;
  size_t obase = (size_t)(qb + row) * CHAN;
  const float* rp0 = xs + row * 257;
#pragma unroll
  for (int j = 0; j < 4; ++j) {
    int d = j * 64 + c8 * 8;
    const float* rp = rp0 + d;
    unsigned int h[8], l[8];
#pragma unroll
    for (int e = 0; e < 8; ++e) fsplit(rp[e], h[e], l[e]);
    int4 ph, pl;
    ph.x = (int)(h[0] | (h[1] << 16)); ph.y = (int)(h[2] | (h[3] << 16));
    ph.z = (int)(h[4] | (h[5] << 16)); ph.w = (int)(h[6] | (h[7] << 16));
    pl.x = (int)(l[0] | (l[1] << 16)); pl.y = (int)(l[2] | (l[3] << 16));
    pl.z = (int)(l[4] | (l[5] << 16)); pl.w = (int)(l[6] | (l[7] << 16));
    *(int4*)(Xh + obase + d) = ph;
    *(int4*)(Xl + obase + d) = pl;
  }
}

// ---------------- dist_mfma: split-bf16 MFMA distances + argmin ----------------
// dot = xh*wh + xl*wh + xh*wl  (error ~1e-3) ; score = wn[k] - 2*dot
__global__ __launch_bounds__(512) void dist_mfma(const unsigned short* __restrict__ Xh,
                                                 const unsigned short* __restrict__ Xl,
                                                 const unsigned short* __restrict__ Wh,
                                                 const unsigned short* __restrict__ Wl,
                                                 const float* __restrict__ wn,
                                                 float* __restrict__ idx_out) {
  __shared__ float rB1[2][64], rB2[2][64];
  __shared__ int   rI1[2][64];
  int t = threadIdx.x;
  int w = t >> 6, l = t & 63;
  int qg = w & 3, kg = w >> 2;
  int qb = blockIdx.x * 64;
  int lr = l & 15, lc = l >> 4;

  bf16x8 ah[8], al[8];
  {
    size_t aoff = (size_t)(qb + qg * 16 + lr) * CHAN + lc * 8;
#pragma unroll
    for (int c = 0; c < 8; ++c) {
      ah[c] = *(const bf16x8*)(Xh + aoff + c * 32);
      al[c] = *(const bf16x8*)(Xl + aoff + c * 32);
    }
  }

  float b1[4] = {3.4e38f, 3.4e38f, 3.4e38f, 3.4e38f};
  float b2[4] = {3.4e38f, 3.4e38f, 3.4e38f, 3.4e38f};
  int   i1[4] = {0, 0, 0, 0};

  size_t woff0 = (size_t)(kg * 1024 + lr) * CHAN + lc * 8;

  for (int it = 0; it < 64; ++it) {
    size_t woff = woff0 + (size_t)it * 16 * CHAN;
    f32x4 acc = {0.f, 0.f, 0.f, 0.f};
#pragma unroll
    for (int c = 0; c < 8; ++c) {
      bf16x8 bh = *(const bf16x8*)(Wh + woff + c * 32);
      bf16x8 bl = *(const bf16x8*)(Wl + woff + c * 32);
      acc = __builtin_amdgcn_mfma_f32_16x16x32_bf16(ah[c], bh, acc, 0, 0, 0);
      acc = __builtin_amdgcn_mfma_f32_16x16x32_bf16(al[c], bh, acc, 0, 0, 0);
      acc = __builtin_amdgcn_mfma_f32_16x16x32_bf16(ah[c], bl, acc, 0, 0, 0);
    }
    int k = kg * 1024 + it * 16 + lr;
    float wnk = wn[k];
#pragma unroll
    for (int r = 0; r < 4; ++r) {
      float sc = fmaf(-2.0f, acc[r], wnk);
      bool lt = sc < b1[r];
      b2[r] = fminf(b2[r], fmaxf(sc, b1[r]));
      b1[r] = lt ? sc : b1[r];
      i1[r] = lt ? k : i1[r];
    }
  }

  // reduce across the 16 code-lanes (xor over bits 0..3)
#pragma unroll
  for (int m = 1; m < 16; m <<= 1) {
#pragma unroll
    for (int r = 0; r < 4; ++r) {
      float ob1 = __shfl_xor(b1[r], m);
      int   oi1 = __shfl_xor(i1[r], m);
      float ob2 = __shfl_xor(b2[r], m);
      bool sw = (ob1 < b1[r]) || (ob1 == b1[r] && oi1 < i1[r]);
      b2[r] = fminf(fmaxf(b1[r], ob1), fminf(b2[r], ob2));
      b1[r] = sw ? ob1 : b1[r];
      i1[r] = sw ? oi1 : i1[r];
    }
  }
  if (lr == 0) {
#pragma unroll
    for (int r = 0; r < 4; ++r) {
      int ql = qg * 16 + lc * 4 + r;
      rB1[kg][ql] = b1[r]; rI1[kg][ql] = i1[r]; rB2[kg][ql] = b2[r];
    }
  }
  __syncthreads();
  if (t < 64) {
    float B1 = rB1[0][t]; int I1 = rI1[0][t]; float B2 = rB2[0][t];
    float c1 = rB1[1][t]; int ci = rI1[1][t]; float c2 = rB2[1][t];
    bool sw = (c1 < B1) || (c1 == B1 && ci < I1);
    float nb2 = fminf(fmaxf(B1, c1), fminf(B2, c2));
    float nb1 = sw ? c1 : B1;
    int   ni  = sw ? ci : I1;
    bool flag = (nb2 - nb1) < 0.05f;
    idx_out[qb + t] = flag ? -(float)(ni + 1) : (float)ni;
  }
}

// ---------------- refine: fp64 exact re-scan of flagged queries ----------------
__global__ __launch_bounds__(256) void refine(const float* __restrict__ X,
                                              const float* __restrict__ W,
                                              float* __restrict__ idx_out) {
  int n = blockIdx.x;
  if (idx_out[n] >= 0.f) return;
  int t = threadIdx.x;
  int b = n / S_SP, s = n % S_SP;

  __shared__ double xd[CHAN];
  xd[t] = (double)X[(size_t)b * CS + (size_t)t * S_SP + s];
  __syncthreads();

  double best = 1e300;
  int bi = 1 << 30;
  for (int j = 0; j < 8; ++j) {
    int k = t * 8 + j;
    const float* Wp = W + (size_t)k * CHAN;
    double dsum = 0.0;
    for (int d = 0; d < CHAN; ++d) {
      double df = xd[d] - (double)Wp[d];
      dsum = fma(df, df, dsum);
    }
    if (dsum < best) { best = dsum; bi = k; }
  }

  __shared__ double rv[256];
  __shared__ int    ri[256];
  rv[t] = best; ri[t] = bi;
  __syncthreads();
  for (int off = 128; off > 0; off >>= 1) {
    if (t < off) {
      if (rv[t + off] < rv[t] || (rv[t + off] == rv[t] && ri[t + off] < ri[t])) {
        rv[t] = rv[t + off]; ri[t] = ri[t + off];
      }
    }
    __syncthreads();
  }
  if (t == 0) idx_out[n] = (float)ri[0];
}

// ---------------- scatter_stats: gather quantized, one-hot, histogram, loss ----------------
__global__ __launch_bounds__(256) void scatter_stats(const float* __restrict__ X,
                                                     const float* __restrict__ W,
                                                     float* __restrict__ outF,
                                                     int* __restrict__ counts,
                                                     float* __restrict__ loss_acc) {
  __shared__ int h[KCODES];
  __shared__ float wred[4];
  int t = threadIdx.x;
  for (int j = t; j < KCODES; j += 256) h[j] = 0;
  __syncthreads();

  int n = blockIdx.x * 256 + t;
  int idx = (int)outF[OFF_IDX + n];
  atomicAdd(&h[idx], 1);
  outF[OFF_ENC + (size_t)n * KCODES + idx] = 1.0f;

  int b = n / S_SP, s = n % S_SP;
  const float* Wp = W + (size_t)idx * CHAN;
  const float* xp = X + (size_t)b * CS + s;
  float* qp = outF + OFF_Q + (size_t)b * CS + s;

  float lsum = 0.f;
#pragma unroll 4
  for (int c = 0; c < CHAN; ++c) {
    float wv = Wp[c];
    float xv = xp[(size_t)c * S_SP];
    qp[(size_t)c * S_SP] = wv;
    float df = wv - xv;
    lsum = fmaf(df, df, lsum);
  }

  for (int off = 32; off; off >>= 1) lsum += __shfl_down(lsum, off);
  if ((t & 63) == 0) wred[t >> 6] = lsum;
  __syncthreads();
  if (t == 0) atomicAdd(loss_acc, wred[0] + wred[1] + wred[2] + wred[3]);

  for (int j = t; j < KCODES; j += 256) {
    int v = h[j];
    if (v) atomicAdd(&counts[j], v);
  }
}

// ---------------- finalize ----------------
__global__ __launch_bounds__(256) void finalize(const int* __restrict__ counts,
                                                const float* __restrict__ loss_acc,
                                                float* __restrict__ outF) {
  __shared__ double red[256];
  int t = threadIdx.x;
  double H = 0.0;
  for (int k = t; k < KCODES; k += 256) {
    double p = (double)counts[k] / (double)NQ;
    H += p * log(p + 1e-10);
  }
  red[t] = H;
  __syncthreads();
  for (int off = 128; off > 0; off >>= 1) {
    if (t < off) red[t] += red[t + off];
    __syncthreads();
  }
  if (t == 0) {
    outF[0] = 0.25f * (loss_acc[0] / 7077888.0f);
    outF[OFF_PPL] = (float)exp(-red[0]);
  }
}

extern "C" void kernel_launch(void* const* d_in, const int* in_sizes, int n_in,
                              void* d_out, int out_size, void* d_ws, size_t ws_size,
                              hipStream_t stream) {
  const float* X = (const float*)d_in[0];
  const float* W = (const float*)d_in[1];
  float* outF = (float*)d_out;
  char* ws = (char*)d_ws;
  float* wn       = (float*)ws;                       // 8 KB
  int*   counts   = (int*)(ws + 8192);                // 8 KB
  float* loss_acc = (float*)(ws + 16384);             // 16 B
  unsigned short* Wh = (unsigned short*)(ws + 32768);            // 1 MB
  unsigned short* Wl = (unsigned short*)(ws + 32768 + 1048576);  // 1 MB
  unsigned short* Xh = (unsigned short*)(ws + 32768 + 2097152);  // 14.16 MB
  unsigned short* Xl = Xh + (size_t)NQ * CHAN;                    // 14.16 MB

  hipMemsetAsync(ws + 8192, 0, 8192 + 16, stream);
  hipMemsetAsync((char*)d_out + OFF_ENC * 4, 0, (size_t)NQ * KCODES * 4, stream);

  prep_w<<<256, 256, 0, stream>>>(W, Wh, Wl, wn);
  prep_x<<<NQ / 32, 256, 0, stream>>>(X, Xh, Xl);
  dist_mfma<<<NQ / 64, 512, 0, stream>>>(Xh, Xl, Wh, Wl, wn, outF + OFF_IDX);
  refine<<<NQ, 256, 0, stream>>>(X, W, outF + OFF_IDX);
  scatter_stats<<<NQ / 256, 256, 0, stream>>>(X, W, outF, counts, loss_acc);
  finalize<<<1, 256, 0, stream>>>(counts, loss_acc, outF);
}

// Round 4
// 273.702 us; speedup vs baseline: 8.3155x; 2.7636x over previous
//
#include <hip/hip_runtime.h>

#define S_SP   13824        // 24*24*24 spatial
#define CHAN   256
#define NQ     27648        // 2 * 13824
#define KCODES 2048
#define CS     3538944      // CHAN * S_SP
#define OFF_Q   1
#define OFF_PPL 7077889
#define OFF_ENC 7077890LL
#define OFF_IDX 63700994LL

typedef __bf16 bf16x8 __attribute__((ext_vector_type(8)));
typedef float  f32x4  __attribute__((ext_vector_type(4)));

#define GLOAD_LDS16(g, s)                                                      \
  __builtin_amdgcn_global_load_lds(                                            \
      (const __attribute__((address_space(1))) void*)(g),                      \
      (__attribute__((address_space(3))) void*)(s), 16, 0, 0)

__device__ __forceinline__ unsigned int f2bf(float f) {
  unsigned int u = __float_as_uint(f);
  unsigned int r = u + 0x7FFFu + ((u >> 16) & 1u);   // RNE
  return r >> 16;
}
__device__ __forceinline__ float bf2f(unsigned int h) {
  return __uint_as_float(h << 16);
}
__device__ __forceinline__ void fsplit(float f, unsigned int& hi, unsigned int& lo) {
  hi = f2bf(f);
  float r = f - bf2f(hi);
  lo = f2bf(r);
}

// ---------------- prep_w: fp32 W -> bf16 Wh/Wl, plus wn = ||w||^2 ----------------
__global__ __launch_bounds__(256) void prep_w(const float* __restrict__ W,
                                              unsigned short* __restrict__ Wh,
                                              unsigned short* __restrict__ Wl,
                                              float* __restrict__ wn) {
  int g = blockIdx.x * 256 + threadIdx.x;
  int row = g >> 5;
  int d0 = (g & 31) * 8;
  const float* Wp = W + (size_t)row * CHAN + d0;
  float v[8];
  *(float4*)(v) = *(const float4*)Wp;
  *(float4*)(v + 4) = *(const float4*)(Wp + 4);
  float s = 0.f;
  unsigned int h[8], l[8];
#pragma unroll
  for (int j = 0; j < 8; ++j) {
    s = fmaf(v[j], v[j], s);
    fsplit(v[j], h[j], l[j]);
  }
  int4 ph, pl;
  ph.x = (int)(h[0] | (h[1] << 16)); ph.y = (int)(h[2] | (h[3] << 16));
  ph.z = (int)(h[4] | (h[5] << 16)); ph.w = (int)(h[6] | (h[7] << 16));
  pl.x = (int)(l[0] | (l[1] << 16)); pl.y = (int)(l[2] | (l[3] << 16));
  pl.z = (int)(l[4] | (l[5] << 16)); pl.w = (int)(l[6] | (l[7] << 16));
  *(int4*)(Wh + (size_t)row * CHAN + d0) = ph;
  *(int4*)(Wl + (size_t)row * CHAN + d0) = pl;
  for (int off = 16; off; off >>= 1) s += __shfl_down(s, off);
  if ((threadIdx.x & 31) == 0) wn[row] = s;
}

// ---------------- prep_x: transpose [C][S] -> [n][d], split to bf16 hi/lo ----------------
__global__ __launch_bounds__(256) void prep_x(const float* __restrict__ X,
                                              unsigned short* __restrict__ Xh,
                                              unsigned short* __restrict__ Xl) {
  __shared__ float xs[32 * 257];
  int t = threadIdx.x;
  int qb = blockIdx.x * 32;
  int b = qb / S_SP, s0 = qb % S_SP;
  const float* xp = X + (size_t)b * CS + s0;
  int q = t & 31;
  int db = t >> 5;                 // 0..7
  for (int r = 0; r < 32; ++r) {
    int d = db + (r << 3);
    xs[q * 257 + d] = xp[(size_t)d * S_SP + q];
  }
  __syncthreads();
  int row = t >> 3, c8 = t & 7;
  size_t obase = (size_t)(qb + row) * CHAN;
  const float* rp0 = xs + row * 257;
#pragma unroll
  for (int j = 0; j < 4; ++j) {
    int d = j * 64 + c8 * 8;
    const float* rp = rp0 + d;
    unsigned int h[8], l[8];
#pragma unroll
    for (int e = 0; e < 8; ++e) fsplit(rp[e], h[e], l[e]);
    int4 ph, pl;
    ph.x = (int)(h[0] | (h[1] << 16)); ph.y = (int)(h[2] | (h[3] << 16));
    ph.z = (int)(h[4] | (h[5] << 16)); ph.w = (int)(h[6] | (h[7] << 16));
    pl.x = (int)(l[0] | (l[1] << 16)); pl.y = (int)(l[2] | (l[3] << 16));
    pl.z = (int)(l[4] | (l[5] << 16)); pl.w = (int)(l[6] | (l[7] << 16));
    *(int4*)(Xh + obase + d) = ph;
    *(int4*)(Xl + obase + d) = pl;
  }
}

// ---------------- dist_mfma: LDS-staged split-bf16 MFMA + per-wave argmin ----------------
// Block: 4 waves x 32 queries = 128 q; kg = blockIdx&1 picks 1024-code half.
// W tile (16 codes, hi+lo) staged fragment-linear via global_load_lds, double-buffered.
__global__ __launch_bounds__(256, 2) void dist_mfma(const unsigned short* __restrict__ Xh,
                                                    const unsigned short* __restrict__ Xl,
                                                    const unsigned short* __restrict__ Wh,
                                                    const unsigned short* __restrict__ Wl,
                                                    const float* __restrict__ wn,
                                                    float* __restrict__ rB1,
                                                    int* __restrict__ rI1,
                                                    float* __restrict__ rB2) {
  __shared__ __align__(16) unsigned short sW[2][2][4096]; // [buf][hi/lo][chunk*512 + lane*8]
  __shared__ float wnl[1024];
  int t = threadIdx.x;
  int w = t >> 6, l = t & 63;
  int lr = l & 15, lc = l >> 4;
  int kg = blockIdx.x & 1;
  int qb = (blockIdx.x >> 1) * 128;
  int kofs = kg << 10;

  for (int j = t; j < 1024; j += 256) wnl[j] = wn[kofs + j];

  // A fragments: wave owns 32 queries as 2 sets of 16 rows
  bf16x8 ah[2][8], al[2][8];
#pragma unroll
  for (int s = 0; s < 2; ++s) {
    size_t base = (size_t)(qb + w * 32 + s * 16 + lr) * CHAN + lc * 8;
#pragma unroll
    for (int c = 0; c < 8; ++c) {
      ah[s][c] = *(const bf16x8*)(Xh + base + c * 32);
      al[s][c] = *(const bf16x8*)(Xl + base + c * 32);
    }
  }

  float b1[2][4], b2[2][4]; int i1[2][4];
#pragma unroll
  for (int s = 0; s < 2; ++s)
#pragma unroll
    for (int r = 0; r < 4; ++r) { b1[s][r] = 3.4e38f; b2[s][r] = 3.4e38f; i1[s][r] = 0; }

  // wave w stages hi+lo chunks {w, w+4}; src pre-permuted to fragment order:
  // lane l -> W[krow = kbase + (l&15)][dims c*32 + (l>>4)*8 .. +8]
  auto stage = [&](int buf, int kt) {
    size_t rb = (size_t)(kofs + (kt << 4) + lr) * CHAN + lc * 8;
    GLOAD_LDS16(Wh + rb + w * 32,        &sW[buf][0][w * 512]);
    GLOAD_LDS16(Wh + rb + (w + 4) * 32,  &sW[buf][0][(w + 4) * 512]);
    GLOAD_LDS16(Wl + rb + w * 32,        &sW[buf][1][w * 512]);
    GLOAD_LDS16(Wl + rb + (w + 4) * 32,  &sW[buf][1][(w + 4) * 512]);
  };

  stage(0, 0);
  __syncthreads();

  for (int kt = 0; kt < 64; ++kt) {
    int cur = kt & 1;
    if (kt < 63) stage(cur ^ 1, kt + 1);
    f32x4 a0 = {0.f, 0.f, 0.f, 0.f}, a1 = {0.f, 0.f, 0.f, 0.f};
#pragma unroll
    for (int c = 0; c < 8; ++c) {
      bf16x8 bh = *(const bf16x8*)&sW[cur][0][c * 512 + (l << 3)];
      bf16x8 bl = *(const bf16x8*)&sW[cur][1][c * 512 + (l << 3)];
      a0 = __builtin_amdgcn_mfma_f32_16x16x32_bf16(ah[0][c], bh, a0, 0, 0, 0);
      a1 = __builtin_amdgcn_mfma_f32_16x16x32_bf16(ah[1][c], bh, a1, 0, 0, 0);
      a0 = __builtin_amdgcn_mfma_f32_16x16x32_bf16(al[0][c], bh, a0, 0, 0, 0);
      a1 = __builtin_amdgcn_mfma_f32_16x16x32_bf16(al[1][c], bh, a1, 0, 0, 0);
      a0 = __builtin_amdgcn_mfma_f32_16x16x32_bf16(ah[0][c], bl, a0, 0, 0, 0);
      a1 = __builtin_amdgcn_mfma_f32_16x16x32_bf16(ah[1][c], bl, a1, 0, 0, 0);
    }
    int k = kofs + (kt << 4) + lr;
    float wnk = wnl[(kt << 4) + lr];
#pragma unroll
    for (int r = 0; r < 4; ++r) {
      float s0 = fmaf(-2.0f, a0[r], wnk);
      bool lt0 = s0 < b1[0][r];
      b2[0][r] = fminf(b2[0][r], fmaxf(s0, b1[0][r]));
      b1[0][r] = lt0 ? s0 : b1[0][r];
      i1[0][r] = lt0 ? k : i1[0][r];
      float s1 = fmaf(-2.0f, a1[r], wnk);
      bool lt1 = s1 < b1[1][r];
      b2[1][r] = fminf(b2[1][r], fmaxf(s1, b1[1][r]));
      b1[1][r] = lt1 ? s1 : b1[1][r];
      i1[1][r] = lt1 ? k : i1[1][r];
    }
    __syncthreads();
  }

  // reduce across the 16 code-lanes (xor bits 0..3; lc invariant)
#pragma unroll
  for (int m = 1; m < 16; m <<= 1) {
#pragma unroll
    for (int s = 0; s < 2; ++s)
#pragma unroll
      for (int r = 0; r < 4; ++r) {
        float ob1 = __shfl_xor(b1[s][r], m);
        int   oi  = __shfl_xor(i1[s][r], m);
        float ob2 = __shfl_xor(b2[s][r], m);
        bool sw = (ob1 < b1[s][r]) || (ob1 == b1[s][r] && oi < i1[s][r]);
        b2[s][r] = fminf(fmaxf(b1[s][r], ob1), fminf(b2[s][r], ob2));
        b1[s][r] = sw ? ob1 : b1[s][r];
        i1[s][r] = sw ? oi : i1[s][r];
      }
  }
  if (lr == 0) {
#pragma unroll
    for (int s = 0; s < 2; ++s)
#pragma unroll
      for (int r = 0; r < 4; ++r) {
        int q = qb + w * 32 + s * 16 + lc * 4 + r;
        size_t o = (size_t)kg * NQ + q;
        rB1[o] = b1[s][r]; rI1[o] = i1[s][r]; rB2[o] = b2[s][r];
      }
  }
}

// ---------------- merge: combine kg halves, flag near-ties into compact list ----------------
__global__ __launch_bounds__(256) void merge_k(const float* __restrict__ rB1,
                                               const int* __restrict__ rI1,
                                               const float* __restrict__ rB2,
                                               float* __restrict__ idx_out,
                                               int* __restrict__ flagcount,
                                               int* __restrict__ flaglist) {
  int n = blockIdx.x * 256 + threadIdx.x;
  float B1 = rB1[n]; int I1 = rI1[n]; float B2 = rB2[n];
  float c1 = rB1[NQ + n]; int ci = rI1[NQ + n]; float c2 = rB2[NQ + n];
  bool sw = (c1 < B1) || (c1 == B1 && ci < I1);
  float nb2 = fminf(fmaxf(B1, c1), fminf(B2, c2));
  float nb1 = sw ? c1 : B1;
  int   ni  = sw ? ci : I1;
  if (nb2 - nb1 < 0.05f) {
    int slot = atomicAdd(flagcount, 1);
    flaglist[slot] = n;
    idx_out[n] = 0.0f;        // placeholder, refine2 overwrites
  } else {
    idx_out[n] = (float)ni;
  }
}

// ---------------- refine2: fp64 exact re-scan, compacted list only ----------------
__global__ __launch_bounds__(256) void refine2(const float* __restrict__ X,
                                               const float* __restrict__ W,
                                               const int* __restrict__ flagcount,
                                               const int* __restrict__ flaglist,
                                               float* __restrict__ idx_out) {
  __shared__ double xd[CHAN];
  __shared__ double rv[256];
  __shared__ int    ri[256];
  int t = threadIdx.x;
  int cnt = flagcount[0];
  for (int j = blockIdx.x; j < cnt; j += gridDim.x) {
    __syncthreads();
    int n = flaglist[j];
    int b = n / S_SP, s = n % S_SP;
    xd[t] = (double)X[(size_t)b * CS + (size_t)t * S_SP + s];
    __syncthreads();

    double best = 1e300;
    int bi = 1 << 30;
    for (int jj = 0; jj < 8; ++jj) {
      int k = t * 8 + jj;
      const float* Wp = W + (size_t)k * CHAN;
      double dsum = 0.0;
      for (int d = 0; d < CHAN; ++d) {
        double df = xd[d] - (double)Wp[d];
        dsum = fma(df, df, dsum);
      }
      if (dsum < best) { best = dsum; bi = k; }
    }
    rv[t] = best; ri[t] = bi;
    __syncthreads();
    for (int off = 128; off > 0; off >>= 1) {
      if (t < off) {
        if (rv[t + off] < rv[t] || (rv[t + off] == rv[t] && ri[t + off] < ri[t])) {
          rv[t] = rv[t + off]; ri[t] = ri[t + off];
        }
      }
      __syncthreads();
    }
    if (t == 0) idx_out[n] = (float)ri[0];
  }
}

// ---------------- scatter_stats: gather quantized, one-hot, histogram, loss ----------------
__global__ __launch_bounds__(256) void scatter_stats(const float* __restrict__ X,
                                                     const float* __restrict__ W,
                                                     float* __restrict__ outF,
                                                     int* __restrict__ counts,
                                                     float* __restrict__ loss_acc) {
  __shared__ int h[KCODES];
  __shared__ float wred[4];
  int t = threadIdx.x;
  for (int j = t; j < KCODES; j += 256) h[j] = 0;
  __syncthreads();

  int n = blockIdx.x * 256 + t;
  int idx = (int)outF[OFF_IDX + n];
  atomicAdd(&h[idx], 1);
  outF[OFF_ENC + (size_t)n * KCODES + idx] = 1.0f;

  int b = n / S_SP, s = n % S_SP;
  const float* Wp = W + (size_t)idx * CHAN;
  const float* xp = X + (size_t)b * CS + s;
  float* qp = outF + OFF_Q + (size_t)b * CS + s;

  float lsum = 0.f;
#pragma unroll 4
  for (int c = 0; c < CHAN; ++c) {
    float wv = Wp[c];
    float xv = xp[(size_t)c * S_SP];
    qp[(size_t)c * S_SP] = wv;
    float df = wv - xv;
    lsum = fmaf(df, df, lsum);
  }

  for (int off = 32; off; off >>= 1) lsum += __shfl_down(lsum, off);
  if ((t & 63) == 0) wred[t >> 6] = lsum;
  __syncthreads();
  if (t == 0) atomicAdd(loss_acc, wred[0] + wred[1] + wred[2] + wred[3]);

  for (int j = t; j < KCODES; j += 256) {
    int v = h[j];
    if (v) atomicAdd(&counts[j], v);
  }
}

// ---------------- finalize ----------------
__global__ __launch_bounds__(256) void finalize(const int* __restrict__ counts,
                                                const float* __restrict__ loss_acc,
                                                float* __restrict__ outF) {
  __shared__ double red[256];
  int t = threadIdx.x;
  double H = 0.0;
  for (int k = t; k < KCODES; k += 256) {
    double p = (double)counts[k] / (double)NQ;
    H += p * log(p + 1e-10);
  }
  red[t] = H;
  __syncthreads();
  for (int off = 128; off > 0; off >>= 1) {
    if (t < off) red[t] += red[t + off];
    __syncthreads();
  }
  if (t == 0) {
    outF[0] = 0.25f * (loss_acc[0] / 7077888.0f);
    outF[OFF_PPL] = (float)exp(-red[0]);
  }
}

extern "C" void kernel_launch(void* const* d_in, const int* in_sizes, int n_in,
                              void* d_out, int out_size, void* d_ws, size_t ws_size,
                              hipStream_t stream) {
  const float* X = (const float*)d_in[0];
  const float* W = (const float*)d_in[1];
  float* outF = (float*)d_out;
  char* ws = (char*)d_ws;
  float* wn        = (float*)ws;                    // 8 KB
  int*   counts    = (int*)(ws + 8192);             // 8 KB  [zeroed]
  float* loss_acc  = (float*)(ws + 16384);          // 4 B   [zeroed]
  int*   flagcount = (int*)(ws + 16388);            // 4 B   [zeroed]
  int*   flaglist  = (int*)(ws + 20480);            // NQ*4
  float* rB1       = (float*)(ws + 131072);         // 2*NQ*4
  int*   rI1       = (int*)(ws + 360448);           // 2*NQ*4
  float* rB2       = (float*)(ws + 589824);         // 2*NQ*4
  unsigned short* Wh = (unsigned short*)(ws + 1048576);   // 1 MB
  unsigned short* Wl = (unsigned short*)(ws + 2097152);   // 1 MB
  unsigned short* Xh = (unsigned short*)(ws + 3145728);   // 14.16 MB
  unsigned short* Xl = Xh + (size_t)NQ * CHAN;            // 14.16 MB

  hipMemsetAsync(ws + 8192, 0, 8208, stream);
  hipMemsetAsync((char*)d_out + OFF_ENC * 4, 0, (size_t)NQ * KCODES * 4, stream);

  prep_w<<<256, 256, 0, stream>>>(W, Wh, Wl, wn);
  prep_x<<<NQ / 32, 256, 0, stream>>>(X, Xh, Xl);
  dist_mfma<<<(NQ / 128) * 2, 256, 0, stream>>>(Xh, Xl, Wh, Wl, wn, rB1, rI1, rB2);
  merge_k<<<NQ / 256, 256, 0, stream>>>(rB1, rI1, rB2, outF + OFF_IDX, flagcount, flaglist);
  refine2<<<256, 256, 0, stream>>>(X, W, flagcount, flaglist, outF + OFF_IDX);
  scatter_stats<<<NQ / 256, 256, 0, stream>>>(X, W, outF, counts, loss_acc);
  finalize<<<1, 256, 0, stream>>>(counts, loss_acc, outF);
}

// Round 5
// 268.471 us; speedup vs baseline: 8.4775x; 1.0195x over previous
//
#include <hip/hip_runtime.h>

#define S_SP   13824        // 24*24*24 spatial
#define CHAN   256
#define NQ     27648        // 2 * 13824
#define KCODES 2048
#define CS     3538944      // CHAN * S_SP
#define OFF_Q   1
#define OFF_PPL 7077889
#define OFF_ENC 7077890LL
#define OFF_IDX 63700994LL

typedef __bf16 bf16x8 __attribute__((ext_vector_type(8)));
typedef float  f32x4  __attribute__((ext_vector_type(4)));

#define GLOAD_LDS16(g, s)                                                      \
  __builtin_amdgcn_global_load_lds(                                            \
      (const __attribute__((address_space(1))) void*)(g),                      \
      (__attribute__((address_space(3))) void*)(s), 16, 0, 0)

__device__ __forceinline__ unsigned int f2bf(float f) {
  unsigned int u = __float_as_uint(f);
  unsigned int r = u + 0x7FFFu + ((u >> 16) & 1u);   // RNE
  return r >> 16;
}
__device__ __forceinline__ float bf2f(unsigned int h) {
  return __uint_as_float(h << 16);
}
__device__ __forceinline__ void fsplit(float f, unsigned int& hi, unsigned int& lo) {
  hi = f2bf(f);
  float r = f - bf2f(hi);
  lo = f2bf(r);
}

// ---------------- prep_w: fp32 W -> bf16 Wh/Wl, plus wn = ||w||^2 ----------------
__global__ __launch_bounds__(256) void prep_w(const float* __restrict__ W,
                                              unsigned short* __restrict__ Wh,
                                              unsigned short* __restrict__ Wl,
                                              float* __restrict__ wn) {
  int g = blockIdx.x * 256 + threadIdx.x;
  int row = g >> 5;
  int d0 = (g & 31) * 8;
  const float* Wp = W + (size_t)row * CHAN + d0;
  float v[8];
  *(float4*)(v) = *(const float4*)Wp;
  *(float4*)(v + 4) = *(const float4*)(Wp + 4);
  float s = 0.f;
  unsigned int h[8], l[8];
#pragma unroll
  for (int j = 0; j < 8; ++j) {
    s = fmaf(v[j], v[j], s);
    fsplit(v[j], h[j], l[j]);
  }
  int4 ph, pl;
  ph.x = (int)(h[0] | (h[1] << 16)); ph.y = (int)(h[2] | (h[3] << 16));
  ph.z = (int)(h[4] | (h[5] << 16)); ph.w = (int)(h[6] | (h[7] << 16));
  pl.x = (int)(l[0] | (l[1] << 16)); pl.y = (int)(l[2] | (l[3] << 16));
  pl.z = (int)(l[4] | (l[5] << 16)); pl.w = (int)(l[6] | (l[7] << 16));
  *(int4*)(Wh + (size_t)row * CHAN + d0) = ph;
  *(int4*)(Wl + (size_t)row * CHAN + d0) = pl;
  for (int off = 16; off; off >>= 1) s += __shfl_down(s, off);
  if ((threadIdx.x & 31) == 0) wn[row] = s;
}

// ---------------- prep_x: transpose [C][S] -> [n][d], split to bf16 hi/lo ----------------
__global__ __launch_bounds__(256) void prep_x(const float* __restrict__ X,
                                              unsigned short* __restrict__ Xh,
                                              unsigned short* __restrict__ Xl) {
  __shared__ float xs[32 * 257];
  int t = threadIdx.x;
  int qb = blockIdx.x * 32;
  int b = qb / S_SP, s0 = qb % S_SP;
  const float* xp = X + (size_t)b * CS + s0;
  int q = t & 31;
  int db = t >> 5;                 // 0..7
  for (int r = 0; r < 32; ++r) {
    int d = db + (r << 3);
    xs[q * 257 + d] = xp[(size_t)d * S_SP + q];
  }
  __syncthreads();
  int row = t >> 3, c8 = t & 7;
  size_t obase = (size_t)(qb + row) * CHAN;
  const float* rp0 = xs + row * 257;
#pragma unroll
  for (int j = 0; j < 4; ++j) {
    int d = j * 64 + c8 * 8;
    const float* rp = rp0 + d;
    unsigned int h[8], l[8];
#pragma unroll
    for (int e = 0; e < 8; ++e) fsplit(rp[e], h[e], l[e]);
    int4 ph, pl;
    ph.x = (int)(h[0] | (h[1] << 16)); ph.y = (int)(h[2] | (h[3] << 16));
    ph.z = (int)(h[4] | (h[5] << 16)); ph.w = (int)(h[6] | (h[7] << 16));
    pl.x = (int)(l[0] | (l[1] << 16)); pl.y = (int)(l[2] | (l[3] << 16));
    pl.z = (int)(l[4] | (l[5] << 16)); pl.w = (int)(l[6] | (l[7] << 16));
    *(int4*)(Xh + obase + d) = ph;
    *(int4*)(Xl + obase + d) = pl;
  }
}

// ---------------- dist_mfma: LDS-staged split-bf16 MFMA + per-wave argmin ----------------
__global__ __launch_bounds__(256, 2) void dist_mfma(const unsigned short* __restrict__ Xh,
                                                    const unsigned short* __restrict__ Xl,
                                                    const unsigned short* __restrict__ Wh,
                                                    const unsigned short* __restrict__ Wl,
                                                    const float* __restrict__ wn,
                                                    float* __restrict__ rB1,
                                                    int* __restrict__ rI1,
                                                    float* __restrict__ rB2) {
  __shared__ __align__(16) unsigned short sW[2][2][4096]; // [buf][hi/lo][chunk*512 + lane*8]
  __shared__ float wnl[1024];
  int t = threadIdx.x;
  int w = t >> 6, l = t & 63;
  int lr = l & 15, lc = l >> 4;
  int kg = blockIdx.x & 1;
  int qb = (blockIdx.x >> 1) * 128;
  int kofs = kg << 10;

  for (int j = t; j < 1024; j += 256) wnl[j] = wn[kofs + j];

  bf16x8 ah[2][8], al[2][8];
#pragma unroll
  for (int s = 0; s < 2; ++s) {
    size_t base = (size_t)(qb + w * 32 + s * 16 + lr) * CHAN + lc * 8;
#pragma unroll
    for (int c = 0; c < 8; ++c) {
      ah[s][c] = *(const bf16x8*)(Xh + base + c * 32);
      al[s][c] = *(const bf16x8*)(Xl + base + c * 32);
    }
  }

  float b1[2][4], b2[2][4]; int i1[2][4];
#pragma unroll
  for (int s = 0; s < 2; ++s)
#pragma unroll
    for (int r = 0; r < 4; ++r) { b1[s][r] = 3.4e38f; b2[s][r] = 3.4e38f; i1[s][r] = 0; }

  auto stage = [&](int buf, int kt) {
    size_t rb = (size_t)(kofs + (kt << 4) + lr) * CHAN + lc * 8;
    GLOAD_LDS16(Wh + rb + w * 32,        &sW[buf][0][w * 512]);
    GLOAD_LDS16(Wh + rb + (w + 4) * 32,  &sW[buf][0][(w + 4) * 512]);
    GLOAD_LDS16(Wl + rb + w * 32,        &sW[buf][1][w * 512]);
    GLOAD_LDS16(Wl + rb + (w + 4) * 32,  &sW[buf][1][(w + 4) * 512]);
  };

  stage(0, 0);
  __syncthreads();

  for (int kt = 0; kt < 64; ++kt) {
    int cur = kt & 1;
    if (kt < 63) stage(cur ^ 1, kt + 1);
    f32x4 a0 = {0.f, 0.f, 0.f, 0.f}, a1 = {0.f, 0.f, 0.f, 0.f};
#pragma unroll
    for (int c = 0; c < 8; ++c) {
      bf16x8 bh = *(const bf16x8*)&sW[cur][0][c * 512 + (l << 3)];
      bf16x8 bl = *(const bf16x8*)&sW[cur][1][c * 512 + (l << 3)];
      a0 = __builtin_amdgcn_mfma_f32_16x16x32_bf16(ah[0][c], bh, a0, 0, 0, 0);
      a1 = __builtin_amdgcn_mfma_f32_16x16x32_bf16(ah[1][c], bh, a1, 0, 0, 0);
      a0 = __builtin_amdgcn_mfma_f32_16x16x32_bf16(al[0][c], bh, a0, 0, 0, 0);
      a1 = __builtin_amdgcn_mfma_f32_16x16x32_bf16(al[1][c], bh, a1, 0, 0, 0);
      a0 = __builtin_amdgcn_mfma_f32_16x16x32_bf16(ah[0][c], bl, a0, 0, 0, 0);
      a1 = __builtin_amdgcn_mfma_f32_16x16x32_bf16(ah[1][c], bl, a1, 0, 0, 0);
    }
    int k = kofs + (kt << 4) + lr;
    float wnk = wnl[(kt << 4) + lr];
#pragma unroll
    for (int r = 0; r < 4; ++r) {
      float s0 = fmaf(-2.0f, a0[r], wnk);
      bool lt0 = s0 < b1[0][r];
      b2[0][r] = fminf(b2[0][r], fmaxf(s0, b1[0][r]));
      b1[0][r] = lt0 ? s0 : b1[0][r];
      i1[0][r] = lt0 ? k : i1[0][r];
      float s1 = fmaf(-2.0f, a1[r], wnk);
      bool lt1 = s1 < b1[1][r];
      b2[1][r] = fminf(b2[1][r], fmaxf(s1, b1[1][r]));
      b1[1][r] = lt1 ? s1 : b1[1][r];
      i1[1][r] = lt1 ? k : i1[1][r];
    }
    __syncthreads();
  }

#pragma unroll
  for (int m = 1; m < 16; m <<= 1) {
#pragma unroll
    for (int s = 0; s < 2; ++s)
#pragma unroll
      for (int r = 0; r < 4; ++r) {
        float ob1 = __shfl_xor(b1[s][r], m);
        int   oi  = __shfl_xor(i1[s][r], m);
        float ob2 = __shfl_xor(b2[s][r], m);
        bool sw = (ob1 < b1[s][r]) || (ob1 == b1[s][r] && oi < i1[s][r]);
        b2[s][r] = fminf(fmaxf(b1[s][r], ob1), fminf(b2[s][r], ob2));
        b1[s][r] = sw ? ob1 : b1[s][r];
        i1[s][r] = sw ? oi : i1[s][r];
      }
  }
  if (lr == 0) {
#pragma unroll
    for (int s = 0; s < 2; ++s)
#pragma unroll
      for (int r = 0; r < 4; ++r) {
        int q = qb + w * 32 + s * 16 + lc * 4 + r;
        size_t o = (size_t)kg * NQ + q;
        rB1[o] = b1[s][r]; rI1[o] = i1[s][r]; rB2[o] = b2[s][r];
      }
  }
}

// ---------------- merge_emit: combine kg halves, write one-hot rows, flag ties ----------------
// 8 rows/block; row r written by 32 lanes as nontemporal 8B stores (256B segments).
__global__ __launch_bounds__(256) void merge_emit(const float* __restrict__ rB1,
                                                  const int* __restrict__ rI1,
                                                  const float* __restrict__ rB2,
                                                  float* __restrict__ outF,
                                                  int* __restrict__ flagcount,
                                                  int2* __restrict__ flaglist) {
  int t = threadIdx.x;
  int r = t >> 5, j = t & 31;
  int n = blockIdx.x * 8 + r;

  float B1 = rB1[n]; int I1 = rI1[n]; float B2 = rB2[n];
  float c1 = rB1[NQ + n]; int ci = rI1[NQ + n]; float c2 = rB2[NQ + n];
  bool sw = (c1 < B1) || (c1 == B1 && ci < I1);
  float nb2 = fminf(fmaxf(B1, c1), fminf(B2, c2));
  float nb1 = sw ? c1 : B1;
  int   ni  = sw ? ci : I1;

  if (j == 0) {
    if (nb2 - nb1 < 0.05f) {
      int slot = atomicAdd(flagcount, 1);
      flaglist[slot] = make_int2(n, ni);
    }
    outF[OFF_IDX + n] = (float)ni;     // provisional if flagged; refine2 overwrites
  }

  float* row = outF + OFF_ENC + (size_t)n * KCODES;
#pragma unroll
  for (int k = 0; k < 32; ++k) {
    int col = 2 * j + 64 * k;
    union { float f[2]; unsigned long long u; } v;
    v.f[0] = (col == ni) ? 1.0f : 0.0f;
    v.f[1] = (col + 1 == ni) ? 1.0f : 0.0f;
    __builtin_nontemporal_store(v.u, (unsigned long long*)(row + col));
  }
}

// ---------------- refine2: fp64 exact re-scan of flagged queries + row patch ----------------
__global__ __launch_bounds__(256) void refine2(const float* __restrict__ X,
                                               const float* __restrict__ W,
                                               const int* __restrict__ flagcount,
                                               const int2* __restrict__ flaglist,
                                               float* __restrict__ outF) {
  __shared__ double xd[CHAN];
  __shared__ double rv[256];
  __shared__ int    ri[256];
  int t = threadIdx.x;
  int cnt = flagcount[0];
  for (int jj = blockIdx.x; jj < cnt; jj += gridDim.x) {
    __syncthreads();
    int2 e = flaglist[jj];
    int n = e.x, prov = e.y;
    int b = n / S_SP, s = n % S_SP;
    xd[t] = (double)X[(size_t)b * CS + (size_t)t * S_SP + s];
    __syncthreads();

    double best = 1e300;
    int bi = 1 << 30;
    for (int j8 = 0; j8 < 8; ++j8) {
      int k = t * 8 + j8;
      const float* Wp = W + (size_t)k * CHAN;
      double dsum = 0.0;
      for (int d = 0; d < CHAN; ++d) {
        double df = xd[d] - (double)Wp[d];
        dsum = fma(df, df, dsum);
      }
      if (dsum < best) { best = dsum; bi = k; }
    }
    rv[t] = best; ri[t] = bi;
    __syncthreads();
    for (int off = 128; off > 0; off >>= 1) {
      if (t < off) {
        if (rv[t + off] < rv[t] || (rv[t + off] == rv[t] && ri[t + off] < ri[t])) {
          rv[t] = rv[t + off]; ri[t] = ri[t + off];
        }
      }
      __syncthreads();
    }
    if (t == 0) {
      int fin = ri[0];
      outF[OFF_IDX + n] = (float)fin;
      if (fin != prov) {
        float* row = outF + OFF_ENC + (size_t)n * KCODES;
        row[prov] = 0.0f;
        row[fin]  = 1.0f;
      }
    }
  }
}

// ---------------- scatter_stats: gather quantized, histogram, loss ----------------
// 64 queries/block, 4 channel-groups; 432 blocks for full CU coverage.
__global__ __launch_bounds__(256) void scatter_stats(const float* __restrict__ X,
                                                     const float* __restrict__ W,
                                                     float* __restrict__ outF,
                                                     int* __restrict__ counts,
                                                     float* __restrict__ loss_acc) {
  __shared__ int sidx[64];
  __shared__ float wred[4];
  int t = threadIdx.x;
  int q = t & 63, cg = t >> 6;
  int n = blockIdx.x * 64 + q;
  if (t < 64) {
    int idx = (int)outF[OFF_IDX + n];
    sidx[t] = idx;
    atomicAdd(&counts[idx], 1);
  }
  __syncthreads();
  int idx = sidx[q];
  int b = n / S_SP, s = n % S_SP;   // 13824 % 64 == 0: block never crosses b
  const float* Wp = W + (size_t)idx * CHAN;
  const float* xp = X + (size_t)b * CS + s;
  float* qp = outF + OFF_Q + (size_t)b * CS + s;

  float lsum = 0.f;
#pragma unroll 8
  for (int k = 0; k < 64; ++k) {
    int c = cg + (k << 2);
    float wv = Wp[c];
    float xv = xp[(size_t)c * S_SP];
    qp[(size_t)c * S_SP] = wv;
    float df = wv - xv;
    lsum = fmaf(df, df, lsum);
  }

  for (int off = 32; off; off >>= 1) lsum += __shfl_down(lsum, off);
  if ((t & 63) == 0) wred[t >> 6] = lsum;
  __syncthreads();
  if (t == 0) atomicAdd(loss_acc, wred[0] + wred[1] + wred[2] + wred[3]);
}

// ---------------- finalize ----------------
__global__ __launch_bounds__(256) void finalize(const int* __restrict__ counts,
                                                const float* __restrict__ loss_acc,
                                                float* __restrict__ outF) {
  __shared__ double red[256];
  int t = threadIdx.x;
  double H = 0.0;
  for (int k = t; k < KCODES; k += 256) {
    double p = (double)counts[k] / (double)NQ;
    H += p * log(p + 1e-10);
  }
  red[t] = H;
  __syncthreads();
  for (int off = 128; off > 0; off >>= 1) {
    if (t < off) red[t] += red[t + off];
    __syncthreads();
  }
  if (t == 0) {
    outF[0] = 0.25f * (loss_acc[0] / 7077888.0f);
    outF[OFF_PPL] = (float)exp(-red[0]);
  }
}

extern "C" void kernel_launch(void* const* d_in, const int* in_sizes, int n_in,
                              void* d_out, int out_size, void* d_ws, size_t ws_size,
                              hipStream_t stream) {
  const float* X = (const float*)d_in[0];
  const float* W = (const float*)d_in[1];
  float* outF = (float*)d_out;
  char* ws = (char*)d_ws;
  float* wn        = (float*)ws;                    // 8 KB
  int*   counts    = (int*)(ws + 8192);             // 8 KB  [zeroed]
  float* loss_acc  = (float*)(ws + 16384);          // 4 B   [zeroed]
  int*   flagcount = (int*)(ws + 16388);            // 4 B   [zeroed]
  int2*  flaglist  = (int2*)(ws + 32768);           // 8*NQ = 216 KB
  float* rB1       = (float*)(ws + 262144);         // 2*NQ*4
  int*   rI1       = (int*)(ws + 483328);           // 2*NQ*4
  float* rB2       = (float*)(ws + 704512);         // 2*NQ*4
  unsigned short* Wh = (unsigned short*)(ws + 1048576);   // 1 MB
  unsigned short* Wl = (unsigned short*)(ws + 2097152);   // 1 MB
  unsigned short* Xh = (unsigned short*)(ws + 3145728);   // 14.16 MB
  unsigned short* Xl = Xh + (size_t)NQ * CHAN;            // 14.16 MB

  hipMemsetAsync(ws + 8192, 0, 8200, stream);

  prep_w<<<256, 256, 0, stream>>>(W, Wh, Wl, wn);
  prep_x<<<NQ / 32, 256, 0, stream>>>(X, Xh, Xl);
  dist_mfma<<<(NQ / 128) * 2, 256, 0, stream>>>(Xh, Xl, Wh, Wl, wn, rB1, rI1, rB2);
  merge_emit<<<NQ / 8, 256, 0, stream>>>(rB1, rI1, rB2, outF, flagcount, flaglist);
  refine2<<<256, 256, 0, stream>>>(X, W, flagcount, flaglist, outF);
  scatter_stats<<<NQ / 64, 256, 0, stream>>>(X, W, outF, counts, loss_acc);
  finalize<<<1, 256, 0, stream>>>(counts, loss_acc, outF);
}